// Round 12
// baseline (187.568 us; speedup 1.0000x reference)
//
#include <hip/hip_runtime.h>
#include <hip/hip_bf16.h>

using bf16 = __hip_bfloat16;
typedef short bf16x8 __attribute__((ext_vector_type(8)));
typedef float f32x4 __attribute__((ext_vector_type(4)));

#define DD 256
#define MTOT 65536   // B*QH*QW = 16*64*64

static __device__ __forceinline__ short f2bs(float f) {
    bf16 h = __float2bfloat16(f);          // RNE
    return *reinterpret_cast<short*>(&h);
}
static __device__ __forceinline__ float bs2f(short s) {
    unsigned u = (unsigned)(unsigned short)s << 16;
    return __uint_as_float(u);
}

// async global->LDS, 16B per lane; LDS dest = wave-uniform base + lane*16
static __device__ __forceinline__ void gll16(const void* g, void* l) {
    __builtin_amdgcn_global_load_lds(
        (const __attribute__((address_space(1))) unsigned int*)g,
        (__attribute__((address_space(3))) unsigned int*)l, 16, 0, 0);
}

// Pre-swizzled BT layout in GLOBAL: element (n = out col, k) at flat
//   n*256 + (((k>>3) ^ (n&7)) << 3 | (k&7))
// 16B-granule XOR closed within each 64-k slice -> LDS staging is a linear
// copy, ds_read at [n][lg ^ (n&7)] bank-optimal (R5/R7: 0 conflicts).
static __device__ __forceinline__ int swz_idx(int n, int k) {
    return n * 256 + ((((k >> 3) ^ (n & 7)) << 3) | (k & 7));
}

// ---------------- K0: convert+transpose+swizzle Wk, Wm (f32 -> bf16) ----------------
__global__ __launch_bounds__(256) void k_transpose(
    const float* __restrict__ Wk, const float* __restrict__ Wm,
    bf16* __restrict__ WkT, bf16* __restrict__ WmT)
{
    int idx = blockIdx.x * 256 + threadIdx.x;
    int which = idx >> 16, e = idx & 65535;
    int i = e >> 8, j = e & 255;               // in[i][j]: i = k, j = n
    const float* src = which == 0 ? Wk : Wm;
    bf16*        dst = which == 0 ? WkT : WmT;
    dst[swz_idx(j, i)] = __float2bfloat16(src[e]);
}

// ---------------- K0b: weight folding: WC = Wb @ [Woff|WA], bc = bb@[Woff|WA] + [boff|bA] ----
__global__ __launch_bounds__(256) void k_prep(
    const float* __restrict__ Wb, const float* __restrict__ bb,
    const float* __restrict__ Woff, const float* __restrict__ boff,
    const float* __restrict__ WA, const float* __restrict__ bA,
    bf16* __restrict__ WCt, float* __restrict__ bc)
{
    __shared__ float colw[256];
    __shared__ float red[256];
    int j = blockIdx.x, t = threadIdx.x;
    colw[t] = (j < 64) ? Woff[t * 64 + j] : WA[t * 32 + (j - 64)];
    red[t] = bb[t] * ((j < 64) ? Woff[t * 64 + j] : WA[t * 32 + (j - 64)]);
    __syncthreads();
    float v = 0.f;
    const float* wbrow = Wb + (size_t)t * 256;   // WC[k=t][j] = sum_i Wb[t][i]*colw[i]
#pragma unroll 8
    for (int i = 0; i < 256; ++i) v += wbrow[i] * colw[i];
    WCt[swz_idx(j, t)] = __float2bfloat16(v);
    for (int s = 128; s > 0; s >>= 1) {
        __syncthreads();
        if (t < s) red[t] += red[t + s];
    }
    if (t == 0) bc[j] = red[0] + ((j < 64) ? boff[j] : bA[j - 64]);
}

// ---------------- double-buffered global_load_lds MFMA mainloop (R7, unchanged) ----------------
template <int NTW, int NCOLS, bool AF32>
static __device__ __forceinline__ void gemm_lds2(
    const void* __restrict__ Av, const bf16* __restrict__ BTswz,
    bf16* __restrict__ Bs, char* __restrict__ As,
    int row0, int tid, f32x4 (&acc)[2][NTW])
{
    const int wave = tid >> 6, lane = tid & 63;
    const int rg = wave >> 1, cg = wave & 1;
    const int rsub = lane & 15, kg = lane >> 4;
    constexpr int SB = NCOLS / 32;
    constexpr int SA = AF32 ? 4 : 2;
    constexpr int ABYTES = AF32 ? 16384 : 8192;

    auto stageB = [&](int s) {
#pragma unroll
        for (int i = 0; i < SB; ++i) {
            int cc = wave * SB + i;
            int i16 = cc * 64 + lane;
            int n = i16 >> 3, lg = i16 & 7;
            gll16(BTswz + (size_t)n * 256 + s * 64 + lg * 8, (char*)Bs + (size_t)i16 * 16);
        }
    };
    auto stageA = [&](int s, int buf) {
#pragma unroll
        for (int i = 0; i < SA; ++i) {
            if constexpr (AF32) {
                int cc = wave * 4 + i;
                int row = cc * 4 + (lane >> 4);
                int g = (lane & 15) ^ (row & 15);
                gll16((const float*)Av + (size_t)(row0 + row) * DD + s * 64 + g * 4,
                      As + (size_t)buf * ABYTES + cc * 1024 + lane * 16);
            } else {
                int cc = wave * 2 + i;
                int row = cc * 8 + (lane >> 3);
                int g = (lane & 7) ^ (row & 7);
                gll16((const bf16*)Av + (size_t)(row0 + row) * DD + s * 64 + g * 8,
                      As + (size_t)buf * ABYTES + cc * 1024 + lane * 16);
            }
        }
    };

    stageA(0, 0);
    int cur = 0;
#pragma unroll
    for (int s = 0; s < 4; ++s) {
        stageB(s);
        if (s < 3) {
            stageA(s + 1, cur ^ 1);
            asm volatile("s_waitcnt vmcnt(%0)" :: "i"(SA) : "memory");
        } else {
            asm volatile("s_waitcnt vmcnt(0)" ::: "memory");
        }
        __builtin_amdgcn_s_barrier();
#pragma unroll
        for (int kkl = 0; kkl < 2; ++kkl) {
            bf16x8 afr[2];
#pragma unroll
            for (int st = 0; st < 2; ++st) {
                int row = rg * 32 + st * 16 + rsub;
                if constexpr (AF32) {
                    const char* base = As + cur * ABYTES + row * 256;
                    int G0 = kkl * 8 + kg * 2;
                    f32x4 v0 = *(const f32x4*)(base + ((G0 ^ (row & 15)) << 4));
                    f32x4 v1 = *(const f32x4*)(base + (((G0 + 1) ^ (row & 15)) << 4));
                    bf16x8 a;
#pragma unroll
                    for (int e = 0; e < 4; ++e) { a[e] = f2bs(v0[e]); a[e + 4] = f2bs(v1[e]); }
                    afr[st] = a;
                } else {
                    const char* base = As + cur * ABYTES + row * 128;
                    int g = kkl * 4 + kg;
                    afr[st] = *(const bf16x8*)(base + ((g ^ (row & 7)) << 4));
                }
            }
            int lg = kkl * 4 + kg;
#pragma unroll
            for (int nt = 0; nt < NTW; ++nt) {
                int n = cg * (NTW * 16) + nt * 16 + rsub;
                bf16x8 b = *(const bf16x8*)((const char*)Bs + (size_t)n * 128 + ((lg ^ (n & 7)) << 4));
                acc[0][nt] = __builtin_amdgcn_mfma_f32_16x16x32_bf16(afr[0], b, acc[0][nt], 0, 0, 0);
                acc[1][nt] = __builtin_amdgcn_mfma_f32_16x16x32_bf16(afr[1], b, acc[1][nt], 0, 0, 0);
            }
        }
        asm volatile("s_waitcnt lgkmcnt(0)" ::: "memory");
        __builtin_amdgcn_s_barrier();
        cur ^= 1;
    }
}

// ---------------- K1: [off | A] = src @ WC + bc ; softmax(A) over K=4 per head ----------------
__global__ __launch_bounds__(256) void k_offA(
    const float* __restrict__ src, const bf16* __restrict__ WCt, const float* __restrict__ bc,
    float* __restrict__ off_ws, float* __restrict__ A_ws)
{
    __shared__ __align__(16) bf16 Bs[96 * 64];    // 12 KB
    __shared__ __align__(16) char As[2 * 16384];  // 32 KB f32 dbuf
    int tid = threadIdx.x, lane = tid & 63, wave = tid >> 6;
    int row0 = blockIdx.x * 64;
    f32x4 acc[2][3] = {};
    gemm_lds2<3, 96, true>(src, WCt, Bs, As, row0, tid, acc);
    int col = lane & 15;
    int jbase = (wave & 1) * 48;
    int rb = row0 + (wave >> 1) * 32 + ((lane >> 4) << 2);
#pragma unroll
    for (int mt = 0; mt < 2; ++mt) {
#pragma unroll
        for (int nt = 0; nt < 3; ++nt) {
            int j = jbase + nt * 16 + col;          // 0..95
            if (j < 64) {                           // offsets
                float bias = bc[j];
#pragma unroll
                for (int r = 0; r < 4; ++r) {
                    int m = rb + mt * 16 + r;
                    off_ws[(size_t)m * 64 + j] = acc[mt][nt][r] + bias;
                }
            } else {                                // A logits, ac = j-64 in 0..31
                int ac = j - 64;                    // head = ac>>2, slot = ac&3
                float bias = bc[j];
#pragma unroll
                for (int r = 0; r < 4; ++r) {
                    int m = rb + mt * 16 + r;
                    float v  = acc[mt][nt][r] + bias;
                    float mx = fmaxf(v, __shfl_xor(v, 1));
                    mx       = fmaxf(mx, __shfl_xor(mx, 2));
                    float e  = __expf(v - mx);
                    float su = e + __shfl_xor(e, 1);
                    su      += __shfl_xor(su, 2);
                    A_ws[(size_t)m * 32 + ac] = e / su;
                }
            }
        }
    }
}

// ---------------- K2: kf = keys @ Wk + bk -> bf16 head-split [(b*8+h)*4096 + pix][32] ----
__global__ __launch_bounds__(256) void k_gemm_kf(
    const float* __restrict__ keys, const bf16* __restrict__ WkT,
    const float* __restrict__ bk, bf16* __restrict__ kf)
{
    __shared__ __align__(16) bf16 Bs[256 * 64];
    __shared__ __align__(16) char As[2 * 16384];
    int tid = threadIdx.x, lane = tid & 63, wave = tid >> 6;
    int row0 = blockIdx.x * 64;
    f32x4 acc[2][8] = {};
    gemm_lds2<8, 256, true>(keys, WkT, Bs, As, row0, tid, acc);
    int col = lane & 15;
    int jbase = (wave & 1) * 128;
    int rb = row0 + (wave >> 1) * 32 + ((lane >> 4) << 2);
#pragma unroll
    for (int mt = 0; mt < 2; ++mt)
#pragma unroll
        for (int nt = 0; nt < 8; ++nt) {
            int j = jbase + nt * 16 + col;         // head h=j>>5, channel c=j&31
            float bias = bk[j];
#pragma unroll
            for (int r = 0; r < 4; ++r) {
                int m = rb + mt * 16 + r;          // b = m>>12, pix = m&4095
                size_t dst = (((size_t)(m >> 12) * 8 + (j >> 5)) * 4096 + (m & 4095)) * 32 + (j & 31);
                kf[dst] = __float2bfloat16(acc[mt][nt][r] + bias);
            }
        }
}

// ---------------- K3: bilinear gather, thread = (query, head) x 32 channels ----------------
// Grid 2048 (8 blocks/CU in one dispatch wave). bid&7 = XCD slot owning 2 batches
// -> kf working set per L2 = 2 MB. Per thread: 3 vector loads -> 16 independent
// 64B corner loads -> 32-channel accumulate (weight math computed once per (m,h)).
__global__ __launch_bounds__(256) void k_sample(
    const float* __restrict__ ref_point, const float* __restrict__ off_ws,
    const float* __restrict__ A_ws, const bf16* __restrict__ kf,
    bf16* __restrict__ feat)
{
    int bid = blockIdx.x;
    int xcd = bid & 7, within = bid >> 3;      // within 0..255
    int b = xcd * 2 + (within >> 7);           // batch 0..15
    int pixblk = within & 127;                 // 128 blocks x 32 queries = 4096
    int t  = threadIdx.x;
    int ml = t >> 3, h = t & 7;                // 32 queries x 8 heads
    int pix = pixblk * 32 + ml;
    int m  = (b << 12) + pix;
    int rbatch = (b * 8 + h) & 15;             // faithful: ref batch = (b*H+h) % B
    const float* rp = ref_point + ((size_t)rbatch * 4096 + pix) * 2;
    float rx = rp[0] * 63.0f;
    float ry = rp[1] * 63.0f;
    const bf16* kfh = kf + ((size_t)(b * 8 + h) * 4096) * 32;
    f32x4 o0 = *(const f32x4*)(off_ws + (size_t)m * 64 + h * 8);
    f32x4 o1 = *(const f32x4*)(off_ws + (size_t)m * 64 + h * 8 + 4);
    f32x4 av = *(const f32x4*)(A_ws  + (size_t)m * 32 + h * 4);
    float acc[32] = {};
#pragma unroll
    for (int k = 0; k < 4; ++k) {
        float ox = (k < 2) ? o0[2 * k] : o1[2 * k - 4];
        float oy = (k < 2) ? o0[2 * k + 1] : o1[2 * k - 3];
        float a  = av[k];
        float px = (rx + ox) * (64.0f / 63.0f) - 0.5f;   // align_corners=False unnormalize
        float py = (ry + oy) * (64.0f / 63.0f) - 0.5f;
        float x0 = floorf(px), y0 = floorf(py);
        float wx1 = px - x0, wy1 = py - y0;
        int xi = (int)x0, yi = (int)y0;
        float ax0 = (1.f - wx1) * ((xi     >= 0 && xi     < 64) ? 1.f : 0.f);
        float ax1 = wx1         * ((xi + 1 >= 0 && xi + 1 < 64) ? 1.f : 0.f);
        float ay0 = (1.f - wy1) * ((yi     >= 0 && yi     < 64) ? a : 0.f);
        float ay1 = wy1         * ((yi + 1 >= 0 && yi + 1 < 64) ? a : 0.f);
        int xc0 = min(max(xi, 0), 63),      xc1 = min(max(xi + 1, 0), 63);
        int yc0 = min(max(yi, 0), 63) * 64, yc1 = min(max(yi + 1, 0), 63) * 64;
        float w00 = ax0 * ay0, w01 = ax1 * ay0, w10 = ax0 * ay1, w11 = ax1 * ay1;
        const bf16* p00 = kfh + (yc0 + xc0) * 32;
        const bf16* p01 = kfh + (yc0 + xc1) * 32;
        const bf16* p10 = kfh + (yc1 + xc0) * 32;
        const bf16* p11 = kfh + (yc1 + xc1) * 32;
#pragma unroll
        for (int g = 0; g < 4; ++g) {      // 4 channel-groups of 8
            bf16x8 v00 = *(const bf16x8*)(p00 + g * 8);
            bf16x8 v01 = *(const bf16x8*)(p01 + g * 8);
            bf16x8 v10 = *(const bf16x8*)(p10 + g * 8);
            bf16x8 v11 = *(const bf16x8*)(p11 + g * 8);
#pragma unroll
            for (int e = 0; e < 8; ++e) {
                acc[g * 8 + e] += w00 * bs2f(v00[e]) + w01 * bs2f(v01[e])
                                + w10 * bs2f(v10[e]) + w11 * bs2f(v11[e]);
            }
        }
    }
    bf16* fp = feat + (size_t)m * DD + h * 32;
#pragma unroll
    for (int g = 0; g < 4; ++g) {
        bf16x8 o;
#pragma unroll
        for (int e = 0; e < 8; ++e) o[e] = f2bs(acc[g * 8 + e]);
        *(bf16x8*)(fp + g * 8) = o;
    }
}

// ---------------- K4: out = feat @ Wm + bm -> f32 (R7) ----------------
__global__ __launch_bounds__(256) void k_gemm_out(
    const bf16* __restrict__ feat, const bf16* __restrict__ WmT,
    const float* __restrict__ bm, float* __restrict__ out)
{
    __shared__ __align__(16) bf16 Bs[256 * 64];
    __shared__ __align__(16) char As[2 * 8192];
    int tid = threadIdx.x, lane = tid & 63, wave = tid >> 6;
    int row0 = blockIdx.x * 64;
    f32x4 acc[2][8] = {};
    gemm_lds2<8, 256, false>(feat, WmT, Bs, As, row0, tid, acc);
    int col = lane & 15;
    int jbase = (wave & 1) * 128;
    int rb = row0 + (wave >> 1) * 32 + ((lane >> 4) << 2);
#pragma unroll
    for (int mt = 0; mt < 2; ++mt)
#pragma unroll
        for (int nt = 0; nt < 8; ++nt) {
            int j = jbase + nt * 16 + col;
            float bias = bm[j];
#pragma unroll
            for (int r = 0; r < 4; ++r)
                out[(size_t)(rb + mt * 16 + r) * DD + j] =
                    acc[mt][nt][r] + bias;
        }
}

extern "C" void kernel_launch(void* const* d_in, const int* in_sizes, int n_in,
                              void* d_out, int out_size, void* d_ws, size_t ws_size,
                              hipStream_t stream)
{
    (void)in_sizes; (void)n_in; (void)out_size; (void)ws_size;
    // setup_inputs order (all float32):
    // 0 query (unused) 1 keys 2 ref_point 3 src_query 4 Wq 5 bq 6 Wb 7 bb
    // 8 Wk 9 bk 10 Woff 11 boff 12 WA 13 bA 14 Wm 15 bm
    const float* keys = (const float*)d_in[1];
    const float* refp = (const float*)d_in[2];
    const float* srcq = (const float*)d_in[3];
    const float* Wb   = (const float*)d_in[6];
    const float* bb   = (const float*)d_in[7];
    const float* Wk   = (const float*)d_in[8];
    const float* bk   = (const float*)d_in[9];
    const float* Woff = (const float*)d_in[10];
    const float* boff = (const float*)d_in[11];
    const float* WA   = (const float*)d_in[12];
    const float* bA   = (const float*)d_in[13];
    const float* Wm   = (const float*)d_in[14];
    const float* bm   = (const float*)d_in[15];

    char* ws = (char*)d_ws;
    bf16*  WkT    = (bf16*)(ws + 0);                    // 128 KiB (swizzled)
    bf16*  WmT    = (bf16*)(ws + 131072);               // 128 KiB (swizzled)
    bf16*  WCt    = (bf16*)(ws + 262144);               // 48 KiB  [96][256] (swizzled, folded)
    float* bc     = (float*)(ws + 311296);              // 384 B
    bf16*  kf_ws  = (bf16*)(ws + 442368 + 33554432ull);             // 32 MiB
    bf16*  feat_ws= (bf16*)(ws + 442368 + 2ull * 33554432ull);      // 32 MiB
    float* off_ws = (float*)(ws + 442368 + 3ull * 33554432ull);     // 16 MiB  [65536][64]
    float* A_ws   = (float*)(ws + 442368 + 3ull * 33554432ull + 16777216ull); // 8 MiB [65536][32]

    float* out = (float*)d_out;

    k_transpose<<<512, 256, 0, stream>>>(Wk, Wm, WkT, WmT);
    k_prep     <<<96, 256, 0, stream>>>(Wb, bb, Woff, boff, WA, bA, WCt, bc);
    k_offA     <<<1024, 256, 0, stream>>>(srcq, WCt, bc, off_ws, A_ws);
    k_gemm_kf  <<<1024, 256, 0, stream>>>(keys, WkT, bk, kf_ws);
    k_sample   <<<2048, 256, 0, stream>>>(refp, off_ws, A_ws, kf_ws, feat_ws);
    k_gemm_out <<<1024, 256, 0, stream>>>(feat_ws, WmT, bm, out);
}

// Round 13
// 118.080 us; speedup vs baseline: 1.5885x; 1.5885x over previous
//
#include <hip/hip_runtime.h>
#include <hip/hip_bf16.h>

using bf16 = __hip_bfloat16;
typedef short bf16x8 __attribute__((ext_vector_type(8)));
typedef float f32x4 __attribute__((ext_vector_type(4)));
typedef unsigned int u32x4 __attribute__((ext_vector_type(4)));

#define DD 256
#define MTOT 65536   // B*QH*QW = 16*64*64

static __device__ __forceinline__ short f2bs(float f) {
    bf16 h = __float2bfloat16(f);          // RNE
    return *reinterpret_cast<short*>(&h);
}
static __device__ __forceinline__ float bs2f(short s) {
    unsigned u = (unsigned)(unsigned short)s << 16;
    return __uint_as_float(u);
}

// async global->LDS, 16B per lane; LDS dest = wave-uniform base + lane*16
static __device__ __forceinline__ void gll16(const void* g, void* l) {
    __builtin_amdgcn_global_load_lds(
        (const __attribute__((address_space(1))) unsigned int*)g,
        (__attribute__((address_space(3))) unsigned int*)l, 16, 0, 0);
}

// Pre-swizzled BT layout in GLOBAL: element (n = out col, k) at flat
//   n*256 + (((k>>3) ^ (n&7)) << 3 | (k&7))
// 16B-granule XOR closed within each 64-k slice -> LDS staging is a linear
// copy, ds_read at [n][lg ^ (n&7)] bank-optimal (R5/R7: 0 conflicts).
static __device__ __forceinline__ int swz_idx(int n, int k) {
    return n * 256 + ((((k >> 3) ^ (n & 7)) << 3) | (k & 7));
}

// ---------------- K0: merged setup: transpose Wk,Wm + weight folding ----------------
// Blocks 0..511: convert+transpose+swizzle Wk/Wm. Blocks 512..607: fold
// WC = Wb @ [Woff|WA] (col j = bid-512), bc = bb@[Woff|WA] + [boff|bA].
__global__ __launch_bounds__(256) void k_setup(
    const float* __restrict__ Wk, const float* __restrict__ Wm,
    bf16* __restrict__ WkT, bf16* __restrict__ WmT,
    const float* __restrict__ Wb, const float* __restrict__ bb,
    const float* __restrict__ Woff, const float* __restrict__ boff,
    const float* __restrict__ WA, const float* __restrict__ bA,
    bf16* __restrict__ WCt, float* __restrict__ bc)
{
    __shared__ float colw[256];
    __shared__ float red[256];
    int bid = blockIdx.x, t = threadIdx.x;
    if (bid < 512) {
        int idx = bid * 256 + t;
        int which = idx >> 16, e = idx & 65535;
        int i = e >> 8, j = e & 255;               // in[i][j]: i = k, j = n
        const float* src = which == 0 ? Wk : Wm;
        bf16*        dst = which == 0 ? WkT : WmT;
        dst[swz_idx(j, i)] = __float2bfloat16(src[e]);
        return;
    }
    int j = bid - 512;                             // 0..95
    float cw = (j < 64) ? Woff[t * 64 + j] : WA[t * 32 + (j - 64)];
    colw[t] = cw;
    red[t] = bb[t] * cw;
    __syncthreads();
    float v = 0.f;
    const float* wbrow = Wb + (size_t)t * 256;     // WC[k=t][j] = sum_i Wb[t][i]*colw[i]
#pragma unroll 8
    for (int i = 0; i < 256; ++i) v += wbrow[i] * colw[i];
    WCt[swz_idx(j, t)] = __float2bfloat16(v);
    for (int s = 128; s > 0; s >>= 1) {
        __syncthreads();
        if (t < s) red[t] += red[t + s];
    }
    if (t == 0) bc[j] = red[0] + ((j < 64) ? boff[j] : bA[j - 64]);
}

// ---------------- double-buffered global_load_lds MFMA mainloop (R7, unchanged) ----------------
template <int NTW, int NCOLS, bool AF32>
static __device__ __forceinline__ void gemm_lds2(
    const void* __restrict__ Av, const bf16* __restrict__ BTswz,
    bf16* __restrict__ Bs, char* __restrict__ As,
    int row0, int tid, f32x4 (&acc)[2][NTW])
{
    const int wave = tid >> 6, lane = tid & 63;
    const int rg = wave >> 1, cg = wave & 1;
    const int rsub = lane & 15, kg = lane >> 4;
    constexpr int SB = NCOLS / 32;
    constexpr int SA = AF32 ? 4 : 2;
    constexpr int ABYTES = AF32 ? 16384 : 8192;

    auto stageB = [&](int s) {
#pragma unroll
        for (int i = 0; i < SB; ++i) {
            int cc = wave * SB + i;
            int i16 = cc * 64 + lane;
            int n = i16 >> 3, lg = i16 & 7;
            gll16(BTswz + (size_t)n * 256 + s * 64 + lg * 8, (char*)Bs + (size_t)i16 * 16);
        }
    };
    auto stageA = [&](int s, int buf) {
#pragma unroll
        for (int i = 0; i < SA; ++i) {
            if constexpr (AF32) {
                int cc = wave * 4 + i;
                int row = cc * 4 + (lane >> 4);
                int g = (lane & 15) ^ (row & 15);
                gll16((const float*)Av + (size_t)(row0 + row) * DD + s * 64 + g * 4,
                      As + (size_t)buf * ABYTES + cc * 1024 + lane * 16);
            } else {
                int cc = wave * 2 + i;
                int row = cc * 8 + (lane >> 3);
                int g = (lane & 7) ^ (row & 7);
                gll16((const bf16*)Av + (size_t)(row0 + row) * DD + s * 64 + g * 8,
                      As + (size_t)buf * ABYTES + cc * 1024 + lane * 16);
            }
        }
    };

    stageA(0, 0);
    int cur = 0;
#pragma unroll
    for (int s = 0; s < 4; ++s) {
        stageB(s);
        if (s < 3) {
            stageA(s + 1, cur ^ 1);
            asm volatile("s_waitcnt vmcnt(%0)" :: "i"(SA) : "memory");
        } else {
            asm volatile("s_waitcnt vmcnt(0)" ::: "memory");
        }
        __builtin_amdgcn_s_barrier();
#pragma unroll
        for (int kkl = 0; kkl < 2; ++kkl) {
            bf16x8 afr[2];
#pragma unroll
            for (int st = 0; st < 2; ++st) {
                int row = rg * 32 + st * 16 + rsub;
                if constexpr (AF32) {
                    const char* base = As + cur * ABYTES + row * 256;
                    int G0 = kkl * 8 + kg * 2;
                    f32x4 v0 = *(const f32x4*)(base + ((G0 ^ (row & 15)) << 4));
                    f32x4 v1 = *(const f32x4*)(base + (((G0 + 1) ^ (row & 15)) << 4));
                    bf16x8 a;
#pragma unroll
                    for (int e = 0; e < 4; ++e) { a[e] = f2bs(v0[e]); a[e + 4] = f2bs(v1[e]); }
                    afr[st] = a;
                } else {
                    const char* base = As + cur * ABYTES + row * 128;
                    int g = kkl * 4 + kg;
                    afr[st] = *(const bf16x8*)(base + ((g ^ (row & 7)) << 4));
                }
            }
            int lg = kkl * 4 + kg;
#pragma unroll
            for (int nt = 0; nt < NTW; ++nt) {
                int n = cg * (NTW * 16) + nt * 16 + rsub;
                bf16x8 b = *(const bf16x8*)((const char*)Bs + (size_t)n * 128 + ((lg ^ (n & 7)) << 4));
                acc[0][nt] = __builtin_amdgcn_mfma_f32_16x16x32_bf16(afr[0], b, acc[0][nt], 0, 0, 0);
                acc[1][nt] = __builtin_amdgcn_mfma_f32_16x16x32_bf16(afr[1], b, acc[1][nt], 0, 0, 0);
            }
        }
        asm volatile("s_waitcnt lgkmcnt(0)" ::: "memory");
        __builtin_amdgcn_s_barrier();
        cur ^= 1;
    }
}

// ---------------- K1: [off | A] = src @ WC + bc ; softmax(A) over K=4 per head ----------------
__global__ __launch_bounds__(256) void k_offA(
    const float* __restrict__ src, const bf16* __restrict__ WCt, const float* __restrict__ bc,
    float* __restrict__ off_ws, float* __restrict__ A_ws)
{
    __shared__ __align__(16) bf16 Bs[96 * 64];    // 12 KB
    __shared__ __align__(16) char As[2 * 16384];  // 32 KB f32 dbuf
    int tid = threadIdx.x, lane = tid & 63, wave = tid >> 6;
    int row0 = blockIdx.x * 64;
    f32x4 acc[2][3] = {};
    gemm_lds2<3, 96, true>(src, WCt, Bs, As, row0, tid, acc);
    int col = lane & 15;
    int jbase = (wave & 1) * 48;
    int rb = row0 + (wave >> 1) * 32 + ((lane >> 4) << 2);
#pragma unroll
    for (int mt = 0; mt < 2; ++mt) {
#pragma unroll
        for (int nt = 0; nt < 3; ++nt) {
            int j = jbase + nt * 16 + col;          // 0..95
            if (j < 64) {                           // offsets
                float bias = bc[j];
#pragma unroll
                for (int r = 0; r < 4; ++r) {
                    int m = rb + mt * 16 + r;
                    off_ws[(size_t)m * 64 + j] = acc[mt][nt][r] + bias;
                }
            } else {                                // A logits, ac = j-64 in 0..31
                int ac = j - 64;                    // head = ac>>2, slot = ac&3
                float bias = bc[j];
#pragma unroll
                for (int r = 0; r < 4; ++r) {
                    int m = rb + mt * 16 + r;
                    float v  = acc[mt][nt][r] + bias;
                    float mx = fmaxf(v, __shfl_xor(v, 1));
                    mx       = fmaxf(mx, __shfl_xor(mx, 2));
                    float e  = __expf(v - mx);
                    float su = e + __shfl_xor(e, 1);
                    su      += __shfl_xor(su, 2);
                    A_ws[(size_t)m * 32 + ac] = e / su;
                }
            }
        }
    }
}

// ---------------- K2: kf = keys @ Wk + bk -> bf16 head-split [(b*8+h)*4096 + pix][32] ----
__global__ __launch_bounds__(256) void k_gemm_kf(
    const float* __restrict__ keys, const bf16* __restrict__ WkT,
    const float* __restrict__ bk, bf16* __restrict__ kf)
{
    __shared__ __align__(16) bf16 Bs[256 * 64];
    __shared__ __align__(16) char As[2 * 16384];
    int tid = threadIdx.x, lane = tid & 63, wave = tid >> 6;
    int row0 = blockIdx.x * 64;
    f32x4 acc[2][8] = {};
    gemm_lds2<8, 256, true>(keys, WkT, Bs, As, row0, tid, acc);
    int col = lane & 15;
    int jbase = (wave & 1) * 128;
    int rb = row0 + (wave >> 1) * 32 + ((lane >> 4) << 2);
#pragma unroll
    for (int mt = 0; mt < 2; ++mt)
#pragma unroll
        for (int nt = 0; nt < 8; ++nt) {
            int j = jbase + nt * 16 + col;         // head h=j>>5, channel c=j&31
            float bias = bk[j];
#pragma unroll
            for (int r = 0; r < 4; ++r) {
                int m = rb + mt * 16 + r;          // b = m>>12, pix = m&4095
                size_t dst = (((size_t)(m >> 12) * 8 + (j >> 5)) * 4096 + (m & 4095)) * 32 + (j & 31);
                kf[dst] = __float2bfloat16(acc[mt][nt][r] + bias);
            }
        }
}

// ---------------- K3: bilinear gather (R11 mapping + hoisted loads) ----------------
// Grid 8192; bid&7 = XCD slot owning 2 batches -> kf per L2 = 2 MB.
// Thread = (q, h, cg): 8 channels, stores contiguous 16B (coalesced).
// 3 phases: (1) all 16 weights+addresses, (2) all 16 corner loads in flight,
// (3) accumulate with 1-op bf16->f32 (u<<16 / u&0xffff0000 per dword pair).
__global__ __launch_bounds__(256) void k_sample(
    const float* __restrict__ ref_point, const float* __restrict__ off_ws,
    const float* __restrict__ A_ws, const bf16* __restrict__ kf,
    bf16* __restrict__ feat)
{
    int bid = blockIdx.x;
    int xcd = bid & 7, within = bid >> 3;
    int b = xcd * 2 + (within >> 9);     // batch 0..15
    int pixblk = within & 511;
    int t  = threadIdx.x;
    int q  = t >> 5;             // 0..7
    int h  = (t >> 2) & 7;       // 0..7
    int cg = t & 3;              // channels cg*8..cg*8+7
    int m  = (b << 12) + pixblk * 8 + q;
    int pix = m & 4095;
    int rbatch = (b * 8 + h) & 15;       // faithful: ref batch = (b*H+h) % B
    const float* rp = ref_point + ((size_t)rbatch * 4096 + pix) * 2;
    float rx = rp[0] * 63.0f;
    float ry = rp[1] * 63.0f;
    const bf16* kfh = kf + ((size_t)(b * 8 + h) * 4096) * 32 + cg * 8;
    f32x4 o0 = *(const f32x4*)(off_ws + (size_t)m * 64 + h * 8);
    f32x4 o1 = *(const f32x4*)(off_ws + (size_t)m * 64 + h * 8 + 4);
    f32x4 av = *(const f32x4*)(A_ws  + (size_t)m * 32 + h * 4);

    // phase 1: weights + addresses for all 4 points
    float w00[4], w01[4], w10[4], w11[4];
    const bf16 *p00[4], *p01[4], *p10[4], *p11[4];
#pragma unroll
    for (int k = 0; k < 4; ++k) {
        float ox = (k < 2) ? o0[2 * k] : o1[2 * k - 4];
        float oy = (k < 2) ? o0[2 * k + 1] : o1[2 * k - 3];
        float a  = av[k];
        float px = (rx + ox) * (64.0f / 63.0f) - 0.5f;   // align_corners=False unnormalize
        float py = (ry + oy) * (64.0f / 63.0f) - 0.5f;
        float x0 = floorf(px), y0 = floorf(py);
        float wx1 = px - x0, wy1 = py - y0;
        int xi = (int)x0, yi = (int)y0;
        float ax0 = (1.f - wx1) * ((xi     >= 0 && xi     < 64) ? 1.f : 0.f);
        float ax1 = wx1         * ((xi + 1 >= 0 && xi + 1 < 64) ? 1.f : 0.f);
        float ay0 = (1.f - wy1) * ((yi     >= 0 && yi     < 64) ? a : 0.f);
        float ay1 = wy1         * ((yi + 1 >= 0 && yi + 1 < 64) ? a : 0.f);
        int xc0 = min(max(xi, 0), 63),      xc1 = min(max(xi + 1, 0), 63);
        int yc0 = min(max(yi, 0), 63) * 64, yc1 = min(max(yi + 1, 0), 63) * 64;
        w00[k] = ax0 * ay0; w01[k] = ax1 * ay0; w10[k] = ax0 * ay1; w11[k] = ax1 * ay1;
        p00[k] = kfh + (yc0 + xc0) * 32;
        p01[k] = kfh + (yc0 + xc1) * 32;
        p10[k] = kfh + (yc1 + xc0) * 32;
        p11[k] = kfh + (yc1 + xc1) * 32;
    }
    // phase 2: issue all 16 independent 16B loads
    bf16x8 v00[4], v01[4], v10[4], v11[4];
#pragma unroll
    for (int k = 0; k < 4; ++k) {
        v00[k] = *(const bf16x8*)p00[k];
        v01[k] = *(const bf16x8*)p01[k];
        v10[k] = *(const bf16x8*)p10[k];
        v11[k] = *(const bf16x8*)p11[k];
    }
    // phase 3: accumulate (1 bit-op + 1 fma per element)
    float acc[8] = {};
#pragma unroll
    for (int k = 0; k < 4; ++k) {
        u32x4 u00 = __builtin_bit_cast(u32x4, v00[k]);
        u32x4 u01 = __builtin_bit_cast(u32x4, v01[k]);
        u32x4 u10 = __builtin_bit_cast(u32x4, v10[k]);
        u32x4 u11 = __builtin_bit_cast(u32x4, v11[k]);
#pragma unroll
        for (int d = 0; d < 4; ++d) {
            acc[2 * d]     += w00[k] * __uint_as_float(u00[d] << 16)
                            + w01[k] * __uint_as_float(u01[d] << 16)
                            + w10[k] * __uint_as_float(u10[d] << 16)
                            + w11[k] * __uint_as_float(u11[d] << 16);
            acc[2 * d + 1] += w00[k] * __uint_as_float(u00[d] & 0xffff0000u)
                            + w01[k] * __uint_as_float(u01[d] & 0xffff0000u)
                            + w10[k] * __uint_as_float(u10[d] & 0xffff0000u)
                            + w11[k] * __uint_as_float(u11[d] & 0xffff0000u);
        }
    }
    bf16x8 o;
#pragma unroll
    for (int e = 0; e < 8; ++e) o[e] = f2bs(acc[e]);
    *(bf16x8*)(feat + (size_t)m * DD + h * 32 + cg * 8) = o;
}

// ---------------- K4: out = feat @ Wm + bm -> f32 (R7) ----------------
__global__ __launch_bounds__(256) void k_gemm_out(
    const bf16* __restrict__ feat, const bf16* __restrict__ WmT,
    const float* __restrict__ bm, float* __restrict__ out)
{
    __shared__ __align__(16) bf16 Bs[256 * 64];
    __shared__ __align__(16) char As[2 * 8192];
    int tid = threadIdx.x, lane = tid & 63, wave = tid >> 6;
    int row0 = blockIdx.x * 64;
    f32x4 acc[2][8] = {};
    gemm_lds2<8, 256, false>(feat, WmT, Bs, As, row0, tid, acc);
    int col = lane & 15;
    int jbase = (wave & 1) * 128;
    int rb = row0 + (wave >> 1) * 32 + ((lane >> 4) << 2);
#pragma unroll
    for (int mt = 0; mt < 2; ++mt)
#pragma unroll
        for (int nt = 0; nt < 8; ++nt) {
            int j = jbase + nt * 16 + col;
            float bias = bm[j];
#pragma unroll
            for (int r = 0; r < 4; ++r)
                out[(size_t)(rb + mt * 16 + r) * DD + j] =
                    acc[mt][nt][r] + bias;
        }
}

extern "C" void kernel_launch(void* const* d_in, const int* in_sizes, int n_in,
                              void* d_out, int out_size, void* d_ws, size_t ws_size,
                              hipStream_t stream)
{
    (void)in_sizes; (void)n_in; (void)out_size; (void)ws_size;
    // setup_inputs order (all float32):
    // 0 query (unused) 1 keys 2 ref_point 3 src_query 4 Wq 5 bq 6 Wb 7 bb
    // 8 Wk 9 bk 10 Woff 11 boff 12 WA 13 bA 14 Wm 15 bm
    const float* keys = (const float*)d_in[1];
    const float* refp = (const float*)d_in[2];
    const float* srcq = (const float*)d_in[3];
    const float* Wb   = (const float*)d_in[6];
    const float* bb   = (const float*)d_in[7];
    const float* Wk   = (const float*)d_in[8];
    const float* bk   = (const float*)d_in[9];
    const float* Woff = (const float*)d_in[10];
    const float* boff = (const float*)d_in[11];
    const float* WA   = (const float*)d_in[12];
    const float* bA   = (const float*)d_in[13];
    const float* Wm   = (const float*)d_in[14];
    const float* bm   = (const float*)d_in[15];

    char* ws = (char*)d_ws;
    bf16*  WkT    = (bf16*)(ws + 0);                    // 128 KiB (swizzled)
    bf16*  WmT    = (bf16*)(ws + 131072);               // 128 KiB (swizzled)
    bf16*  WCt    = (bf16*)(ws + 262144);               // 48 KiB  [96][256] (swizzled, folded)
    float* bc     = (float*)(ws + 311296);              // 384 B
    bf16*  kf_ws  = (bf16*)(ws + 442368 + 33554432ull);             // 32 MiB
    bf16*  feat_ws= (bf16*)(ws + 442368 + 2ull * 33554432ull);      // 32 MiB
    float* off_ws = (float*)(ws + 442368 + 3ull * 33554432ull);     // 16 MiB  [65536][64]
    float* A_ws   = (float*)(ws + 442368 + 3ull * 33554432ull + 16777216ull); // 8 MiB [65536][32]

    float* out = (float*)d_out;

    k_setup    <<<608, 256, 0, stream>>>(Wk, Wm, WkT, WmT, Wb, bb, Woff, boff, WA, bA, WCt, bc);
    k_offA     <<<1024, 256, 0, stream>>>(srcq, WCt, bc, off_ws, A_ws);
    k_gemm_kf  <<<1024, 256, 0, stream>>>(keys, WkT, bk, kf_ws);
    k_sample   <<<8192, 256, 0, stream>>>(refp, off_ws, A_ws, kf_ws, feat_ws);
    k_gemm_out <<<1024, 256, 0, stream>>>(feat_ws, WmT, bm, out);
}